// Round 3
// baseline (27.579 us; speedup 1.0000x reference)
//
#include <hip/hip_runtime.h>
#include <math.h>

// Problem constants (match reference)
constexpr int S = 4096;
constexpr int WPB = 4;                  // waves per block
constexpr int THREADS = 64 * WPB;
constexpr int ROWS_PER_WAVE = 2;
constexpr int ITERS = S / (4 * 64);     // 16 int4 loads per lane per row

__device__ __forceinline__ void epilogue(const float* __restrict__ drowsy,
                                         float* __restrict__ out,
                                         int row, int cnt, int last) {
    const int pos = (last >= 0) ? last : 0;       // argmax of all-zero row is 0
    // max_eye = cnt; max_att = S-1-pos (finite iff pos < S-1)
    float adjustment = 0.0f;
    if (cnt >= 40 && pos <= S - 1 - 40) {         // max_eye>=40 && max_att>=40
        const float excess = (float)(S - 1 - pos) - 40.0f;    // >= 0 here
        adjustment = 0.05f * (1.0f - expf(-excess * (3.0f / 160.0f)));
    }
    float r = drowsy[row] * (1.0f - adjustment);
    out[row] = fminf(fmaxf(r, 0.01f), 1.0f);
}

__global__ __launch_bounds__(THREADS)
void cca_kernel(const float* __restrict__ drowsy,
                const int* __restrict__ gest,
                float* __restrict__ out, int B) {
    const int lane = threadIdx.x & 63;
    const int wid = blockIdx.x * WPB + (threadIdx.x >> 6);  // global wave id
    const int row0 = wid * ROWS_PER_WAVE;
    const int row1 = row0 + 1;
    if (row0 >= B) return;

    const int4* g0 = reinterpret_cast<const int4*>(gest + (size_t)row0 * S);
    const int4* g1 = reinterpret_cast<const int4*>(gest + (size_t)row1 * S);
    const bool has1 = (row1 < B);

    int c0 = 0, l0 = -1;   // count of ones / last index of one, row0
    int c1 = 0, l1 = -1;   // row1

    #pragma unroll
    for (int k = 0; k < ITERS; ++k) {
        const int idx4 = k * 64 + lane;            // coalesced
        const int base = idx4 * 4;
        const int4 a = g0[idx4];
        const int4 b = has1 ? g1[idx4] : make_int4(0, 0, 0, 0);
        c0 += a.x + a.y + a.z + a.w;
        if (a.x) l0 = base;
        if (a.y) l0 = base + 1;
        if (a.z) l0 = base + 2;
        if (a.w) l0 = base + 3;
        c1 += b.x + b.y + b.z + b.w;
        if (b.x) l1 = base;
        if (b.y) l1 = base + 1;
        if (b.z) l1 = base + 2;
        if (b.w) l1 = base + 3;
    }

    // Two interleaved wave-level butterfly reductions (independent DS chains)
    #pragma unroll
    for (int m = 32; m >= 1; m >>= 1) {
        const int tc0 = __shfl_xor(c0, m, 64);
        const int tl0 = __shfl_xor(l0, m, 64);
        const int tc1 = __shfl_xor(c1, m, 64);
        const int tl1 = __shfl_xor(l1, m, 64);
        c0 += tc0; l0 = max(l0, tl0);
        c1 += tc1; l1 = max(l1, tl1);
    }

    // After butterfly, every lane holds the final values: parallel epilogues.
    if (lane == 0)          epilogue(drowsy, out, row0, c0, l0);
    if (lane == 1 && has1)  epilogue(drowsy, out, row1, c1, l1);
}

extern "C" void kernel_launch(void* const* d_in, const int* in_sizes, int n_in,
                              void* d_out, int out_size, void* d_ws, size_t ws_size,
                              hipStream_t stream) {
    const float* drowsy = (const float*)d_in[0]; // [B,1] float32
    const int* gest = (const int*)d_in[1];       // [B,S,1] int32
    float* out = (float*)d_out;                  // [B,1] float32
    const int B = in_sizes[0];                   // 8192

    const int rows_per_block = WPB * ROWS_PER_WAVE;               // 8
    const int grid = (B + rows_per_block - 1) / rows_per_block;   // 1024
    cca_kernel<<<grid, THREADS, 0, stream>>>(drowsy, gest, out, B);
}

// Round 5
// 22.912 us; speedup vs baseline: 1.2037x; 1.2037x over previous
//
#include <hip/hip_runtime.h>
#include <math.h>

// Problem constants (match reference)
constexpr int S = 4096;
constexpr int THREADS = 256;
constexpr int PER_THREAD = S / (THREADS * 4); // 4 int4 loads per thread

typedef int iv4 __attribute__((ext_vector_type(4)));  // native vector: OK for nontemporal builtin

__global__ __launch_bounds__(THREADS)
void cca_kernel(const float* __restrict__ drowsy,
                const int* __restrict__ gest,
                float* __restrict__ out) {
    const int row = blockIdx.x;
    const int t = threadIdx.x;
    const iv4* g4 = reinterpret_cast<const iv4*>(gest + (size_t)row * S);

    int cnt = 0;   // number of ones in row
    int last = -1; // last index where g == 1

    #pragma unroll
    for (int k = 0; k < PER_THREAD; ++k) {
        const int idx4 = k * THREADS + t;   // int4 index within row (coalesced)
        // Nontemporal: streaming read, no reuse -> skip cache allocation (nt flag)
        const iv4 v = __builtin_nontemporal_load(&g4[idx4]);
        const int base = idx4 * 4;
        cnt += v.x + v.y + v.z + v.w;
        // values are 0/1; ascending order, so later assignments are larger idx
        if (v.x) last = base + 0;
        if (v.y) last = base + 1;
        if (v.z) last = base + 2;
        if (v.w) last = base + 3;
    }

    // wave-level reduction (64 lanes)
    #pragma unroll
    for (int m = 1; m < 64; m <<= 1) {
        cnt += __shfl_xor(cnt, m, 64);
        last = max(last, __shfl_xor(last, m, 64));
    }

    __shared__ int s_cnt[THREADS / 64];
    __shared__ int s_last[THREADS / 64];
    const int wave = t >> 6;
    if ((t & 63) == 0) { s_cnt[wave] = cnt; s_last[wave] = last; }
    __syncthreads();

    if (t == 0) {
        int C = 0, L = -1;
        #pragma unroll
        for (int w = 0; w < THREADS / 64; ++w) {
            C += s_cnt[w];
            L = max(L, s_last[w]);
        }
        const int pos = (L >= 0) ? L : 0;   // argmax of all-zero row is 0

        // max_eye = C; max_att = S-1-pos (or -inf if pos == S-1)
        float adjustment = 0.0f;
        if (C >= 40 && pos <= S - 1 - 40) { // max_eye>=40 && max_att>=40 (finite)
            const float max_att = (float)(S - 1 - pos);
            const float excess = max_att - 40.0f;            // >= 0 here
            adjustment = 0.05f * (1.0f - expf(-excess * (3.0f / 160.0f)));
        }
        float r = drowsy[row] * (1.0f - adjustment);
        r = fminf(fmaxf(r, 0.01f), 1.0f);
        out[row] = r;
    }
}

extern "C" void kernel_launch(void* const* d_in, const int* in_sizes, int n_in,
                              void* d_out, int out_size, void* d_ws, size_t ws_size,
                              hipStream_t stream) {
    const float* drowsy = (const float*)d_in[0]; // [B,1] float32
    const int* gest = (const int*)d_in[1];       // [B,S,1] int32
    float* out = (float*)d_out;                  // [B,1] float32
    const int B = in_sizes[0];                   // 8192

    cca_kernel<<<B, THREADS, 0, stream>>>(drowsy, gest, out);
}